// Round 14
// baseline (165.482 us; speedup 1.0000x reference)
//
#include <hip/hip_runtime.h>

typedef unsigned short u16;
typedef unsigned int u32;
typedef __attribute__((ext_vector_type(8))) short short8;
typedef __attribute__((ext_vector_type(4))) float f32x4;

#define B_ 4
#define L_ 4096
#define D_ 1024
#define S_ 16
#define M_ (B_ * L_)   // 16384 rows
#define NBG 64         // scan chunks per batch
#define LC 64          // timesteps per chunk

__device__ __forceinline__ float b2f(u16 h) {
    unsigned u = ((unsigned)h) << 16;
    return __builtin_bit_cast(float, u);
}
__device__ __forceinline__ u16 f2b(float f) {
    unsigned u = __builtin_bit_cast(unsigned, f);
    u += 0x7fffu + ((u >> 16) & 1u);   // RNE
    return (u16)(u >> 16);
}
__device__ __forceinline__ float softplus_f(float z) {
    return z > 20.f ? z : log1pf(__expf(z));
}
__device__ __forceinline__ void gload16(const u16* g, const u16* l) {
    __builtin_amdgcn_global_load_lds(
        (const __attribute__((address_space(1))) u32*)g,
        (__attribute__((address_space(3))) u32*)l, 16, 0, 0);
}

// ---------------- fused: LayerNorm (wave-per-row) + weight transposes + Wp pack ----------------
__global__ __launch_bounds__(256) void ln_prep_kernel(
    const float* __restrict__ x, const float* __restrict__ gamma,
    const float* __restrict__ beta, u16* __restrict__ xout,
    const float* __restrict__ W0, u16* __restrict__ Wt0,
    const float* __restrict__ W1, u16* __restrict__ Wt1,
    const float* __restrict__ WA, const float* __restrict__ WB,
    const float* __restrict__ WC, const float* __restrict__ Wdt,
    u16* __restrict__ Wp) {
    int blk = blockIdx.x, tid = threadIdx.x;
    if (blk < M_ / 4) {
        int w = tid >> 6, lane = tid & 63;
        int row = blk * 4 + w;
        const float* xr = &x[(size_t)row * D_];
        float4 v[4];
        float s = 0.f, q = 0.f;
#pragma unroll
        for (int i = 0; i < 4; i++) {
            v[i] = *(const float4*)&xr[(i * 64 + lane) * 4];
            s += v[i].x + v[i].y + v[i].z + v[i].w;
            q += v[i].x * v[i].x + v[i].y * v[i].y + v[i].z * v[i].z + v[i].w * v[i].w;
        }
#pragma unroll
        for (int o = 32; o > 0; o >>= 1) {
            s += __shfl_xor(s, o);
            q += __shfl_xor(q, o);
        }
        float mu = s * (1.f / D_);
        float rs = rsqrtf(q * (1.f / D_) - mu * mu + 1e-5f);
        u16* orow = &xout[(size_t)row * D_];
#pragma unroll
        for (int i = 0; i < 4; i++) {
            const float4 gv = *(const float4*)&gamma[(i * 64 + lane) * 4];
            const float4 bv = *(const float4*)&beta[(i * 64 + lane) * 4];
            ushort4 o4;
            o4.x = f2b((v[i].x - mu) * rs * gv.x + bv.x);
            o4.y = f2b((v[i].y - mu) * rs * gv.y + bv.y);
            o4.z = f2b((v[i].z - mu) * rs * gv.z + bv.z);
            o4.w = f2b((v[i].w - mu) * rs * gv.w + bv.w);
            *(ushort4*)&orow[(i * 64 + lane) * 4] = o4;
        }
    } else if (blk < M_ / 4 + 2048) {
        int b = blk - M_ / 4;
        const float* W = (b >> 10) ? W1 : W0;
        u16* Wt = (b >> 10) ? Wt1 : Wt0;
        int by = (b >> 5) & 31, bx = b & 31;
        int xx = tid & 31, ty = tid >> 5;
        __shared__ float t[32][33];
        for (int j = ty; j < 32; j += 8)
            t[j][xx] = W[(size_t)(by * 32 + j) * D_ + bx * 32 + xx];
        __syncthreads();
        for (int j = ty; j < 32; j += 8)
            Wt[(size_t)(bx * 32 + j) * D_ + by * 32 + xx] = f2b(t[xx][j]);
    } else {
        int idx = (blk - M_ / 4 - 2048) * 256 + tid;   // 0..65535
        int s = idx >> 10, k = idx & 1023;
        float v;
        if (s < 16)       v = WA[k * 16 + s];
        else if (s < 32)  v = WB[k * 16 + (s - 16)];
        else if (s < 48)  v = WC[k * 16 + (s - 32)];
        else if (s == 48) v = Wdt[k];
        else if (s == 49) v = 1.0f / 1024.0f;
        else              v = 0.f;
        Wp[idx] = f2b(v);
    }
}

// ================= 256x256 GEMM, 4 waves x (128x128)/wave =================
// LDS-ingest-optimized: per-wave 128x128 output halves block LDS read traffic
// (128 KB/tile vs 192 KB for 8-wave 2x4). BK=64, 2 LDS buffers = 128 KiB.
// B fragments read once per tile (held in 64 VGPRs), A region per phase.
// st_16x32 swizzle via inverse-swizzled global source + swizzled ds_read.
// Loose sync: one vmcnt(0) + one s_barrier per K-tile.
// EPI==1: silu(acc+bias) -> bf16 via LDS-coalesced stores
// EPI==2: yrow[row]*acc + bias + resid -> fp32 direct
template <int EPI>
__global__ __launch_bounds__(256, 1) void gemm256(
    const u16* __restrict__ A, const u16* __restrict__ Bt,
    const float* __restrict__ bias, const float* __restrict__ resid,
    const float* __restrict__ yrow,
    u16* __restrict__ outB, float* __restrict__ outF,
    int M, int N, int K, int nTileN) {
    __shared__ u16 sm[65536];   // 128 KiB: [2 buf][A 16384 | B 16384]; epilogue reuses
    const int TILES = K >> 6;

    int nwg = gridDim.x;
    int bid = blockIdx.x;
    int swz = (bid & 7) * (nwg >> 3) + (bid >> 3);
    int bx = swz % nTileN, by = swz / nTileN;
    int rowBase = by * 256, colBase = bx * 256;

    int tid = threadIdx.x;
    int lane = tid & 63, w = tid >> 6;
    int wr = w >> 1, wc = w & 1;        // wave grid 2(M) x 2(N), 128x128 each
    int lr = lane & 15, lg = lane >> 4;
    const unsigned woff = (unsigned)((lr * 32 + lg * 8) ^ ((lr & 8) ? 16 : 0));

    // staging: wave w stages subtile slots {w, w+4} of each region (A and B)
    int pos0 = w >> 1;                   // 0..1 ; second slot pos0+2
    int kblk = w & 1;
    int r = lane >> 2;
    int chunk = (lane & 3) ^ ((r & 8) ? 2 : 0);   // inverse st_16x32 swizzle
    int rowoff0 = (pos0 & 1) * 16;                 // pos0 in {0,1} -> {0,16}
    const u16* gA0 = A  + (size_t)(rowBase + rowoff0 + r) * K + kblk * 32 + chunk * 8;
    const u16* gA1 = gA0 + (size_t)128 * K;        // pos0+2 -> rowoff +128
    const u16* gB0 = Bt + (size_t)(colBase + rowoff0 + r) * K + kblk * 32 + chunk * 8;
    const u16* gB1 = gB0 + (size_t)128 * K;
    const unsigned sub0 = (unsigned)w * 512u;
    const unsigned sub1 = (unsigned)(w + 4) * 512u;

#define STAGE_ALL(sbb, tau)                                                      \
    do {                                                                         \
        _Pragma("unroll")                                                        \
        for (int p = 0; p < 4; p++) {                                            \
            size_t _go = (size_t)p * 32 * K + (size_t)(tau) * 64;                \
            unsigned _rb = (sbb) + (unsigned)p * 4096u;                          \
            gload16(gB0 + _go, &sm[_rb + 16384u + sub0]);                        \
            gload16(gB1 + _go, &sm[_rb + 16384u + sub1]);                        \
            gload16(gA0 + _go, &sm[_rb + sub0]);                                 \
            gload16(gA1 + _go, &sm[_rb + sub1]);                                 \
        }                                                                        \
    } while (0)

    f32x4 acc[8][8] = {};

    // prologue: stage tile 0, drain, publish
    STAGE_ALL(0u, 0);
    asm volatile("s_waitcnt vmcnt(0)" ::: "memory");
    __builtin_amdgcn_s_barrier();

    for (int t = 0; t < TILES; ++t) {
        const unsigned bb = (unsigned)(t & 1) * 32768u;
        const unsigned nb = (unsigned)((t + 1) & 1) * 32768u;
        if (t + 1 < TILES) STAGE_ALL(nb, t + 1);   // full-tile distance to drain
        // B fragments for the whole tile (8 n x 2 ks), held in registers
        short8 bfr[8][2];
#pragma unroll
        for (int n = 0; n < 8; n++) {
            unsigned bo = bb + 16384u + (unsigned)(n >> 1) * 4096u
                        + (unsigned)((n & 1) + (wc << 1)) * 1024u + woff;
            bfr[n][0] = *(const short8*)&sm[bo];
            bfr[n][1] = *(const short8*)&sm[bo + 512u];
        }
        // 4 phases: A region q (m = 2q, 2q+1), 32 MFMA each
#pragma unroll
        for (int q = 0; q < 4; q++) {
            short8 afr[2][2];
#pragma unroll
            for (int dm = 0; dm < 2; dm++) {
                unsigned ao = bb + (unsigned)q * 4096u
                            + (unsigned)(dm + (wr << 1)) * 1024u + woff;
                afr[dm][0] = *(const short8*)&sm[ao];
                afr[dm][1] = *(const short8*)&sm[ao + 512u];
            }
#pragma unroll
            for (int ks = 0; ks < 2; ks++)
#pragma unroll
                for (int dm = 0; dm < 2; dm++)
#pragma unroll
                    for (int n = 0; n < 8; n++)
                        acc[q * 2 + dm][n] = __builtin_amdgcn_mfma_f32_16x16x32_bf16(
                            afr[dm][ks], bfr[n][ks], acc[q * 2 + dm][n], 0, 0, 0);
        }
        if (t + 1 < TILES) asm volatile("s_waitcnt vmcnt(0)" ::: "memory");
        __builtin_amdgcn_s_barrier();
    }
#undef STAGE_ALL

    // ---------- epilogue
    if (EPI == 1) {
        float bcol[8];
#pragma unroll
        for (int n = 0; n < 8; n++) bcol[n] = bias[colBase + wc * 128 + n * 16 + lr];
#pragma unroll
        for (int m = 0; m < 8; m++)
#pragma unroll
            for (int n = 0; n < 8; n++)
#pragma unroll
                for (int j = 0; j < 4; j++) {
                    int row = wr * 128 + m * 16 + lg * 4 + j;
                    int col = wc * 128 + n * 16 + lr;
                    float v = acc[m][n][j] + bcol[n];
                    v = v / (1.f + __expf(-v));     // silu
                    int cbs = (col >> 4) ^ lg;      // chunk swizzle, (row>>2)&3 == lg
                    sm[row * 256 + cbs * 16 + (col & 15)] = f2b(v);
                }
        __syncthreads();
        int half = tid & 1;
#pragma unroll
        for (int rep = 0; rep < 2; rep++) {
            int rr = rep * 128 + (tid >> 1);
            u16* gout = outB + (size_t)(rowBase + rr) * N + colBase;
#pragma unroll
            for (int q = 0; q < 8; q++) {
                int cb = half * 8 + q;
                int cbs = cb ^ ((rr >> 2) & 3);
                *(uint4*)&gout[cb * 16] = *(const uint4*)&sm[rr * 256 + cbs * 16];
            }
        }
    } else {
        float bcol[8];
#pragma unroll
        for (int n = 0; n < 8; n++) bcol[n] = bias[colBase + wc * 128 + n * 16 + lr];
#pragma unroll
        for (int m = 0; m < 8; m++) {
            float yr[4];
#pragma unroll
            for (int j = 0; j < 4; j++)
                yr[j] = yrow[rowBase + wr * 128 + m * 16 + lg * 4 + j];
#pragma unroll
            for (int n = 0; n < 8; n++)
#pragma unroll
                for (int j = 0; j < 4; j++) {
                    int row = rowBase + wr * 128 + m * 16 + lg * 4 + j;
                    int col = colBase + wc * 128 + n * 16 + lr;
                    size_t o = (size_t)row * N + col;
                    outF[o] = acc[m][n][j] * yr[j] + bcol[n] + resid[o];
                }
        }
    }
}

// ---------------- projection GEMM + fused per-chunk scan partials ----------------
__global__ __launch_bounds__(256) void proj_kernel(
    const u16* __restrict__ X, const u16* __restrict__ Wp,
    const float* __restrict__ bA, const float* __restrict__ bB,
    const float* __restrict__ bC, const float* __restrict__ bdt,
    float* __restrict__ Ad, float* __restrict__ Bu, float* __restrict__ Ct,
    float* __restrict__ Pb, float* __restrict__ Qb) {
    __shared__ u16 Xs[2][64][32];
    __shared__ u16 Ws[2][64][32];
    __shared__ float Psh[64][17], Qsh[64][17];
    int rowBase = blockIdx.x * 64;
    int tid = threadIdx.x, lane = tid & 63, w = tid >> 6;
    int lr = lane & 15, lg = lane >> 4;
    f32x4 acc[4] = {};
    const int sr = lane >> 2, sc = (lane & 3) * 8;
    const u16* gX = &X[(size_t)(rowBase + w * 16 + sr) * 1024 + sc];
    const u16* gW = &Wp[(size_t)(w * 16 + sr) * 1024 + sc];

#define PSTAGE(d, k0)                              \
    do {                                           \
        gload16(gX + (k0), &Xs[d][w * 16][0]);     \
        gload16(gW + (k0), &Ws[d][w * 16][0]);     \
    } while (0)

    PSTAGE(0, 0);
    __syncthreads();
    int cur = 0;
    for (int k0 = 0; k0 < 1024; k0 += 32) {
        if (k0 + 32 < 1024) PSTAGE(cur ^ 1, k0 + 32);
        short8 a = *(const short8*)&Xs[cur][w * 16 + lr][lg * 8];
#pragma unroll
        for (int n = 0; n < 4; n++) {
            short8 b = *(const short8*)&Ws[cur][n * 16 + lr][lg * 8];
            acc[n] = __builtin_amdgcn_mfma_f32_16x16x32_bf16(a, b, acc[n], 0, 0, 0);
        }
        __syncthreads();
        cur ^= 1;
    }
#undef PSTAGE
    float bdt0 = bdt[0];
#pragma unroll
    for (int j = 0; j < 4; j++) {
        int rl = w * 16 + lg * 4 + j;              // row within chunk, 0..63
        int row = rowBase + rl;
        float dtr = __shfl(acc[3][j], lg * 16 + 0, 64);   // col 48 = z_dt
        float uv  = __shfl(acc[3][j], lg * 16 + 1, 64);   // col 49 = u (mean)
        float dt = softplus_f(dtr + bdt0);
        float zA = acc[0][j] + bA[lr];
        float zB = acc[1][j] + bB[lr];
        float zC = acc[2][j] + bC[lr];
        size_t o = (size_t)row * 16 + lr;
        float adv = __expf(-dt * softplus_f(zA));
        float buv = zB * dt * uv;
        Ad[o] = adv;
        Bu[o] = buv;
        Ct[o] = zC;
        Psh[rl][lr] = adv;
        Qsh[rl][lr] = buv;
    }
    __syncthreads();
    if (tid < 16) {
        float P = 1.f, Q = 0.f;
        for (int rr = 0; rr < 64; rr++) {
            float pa = Psh[rr][tid];
            P = pa * P;
            Q = pa * Q + Qsh[rr][tid];
        }
        int o = blockIdx.x * S_ + tid;   // blockIdx == b*NBG + g
        Pb[o] = P; Qb[o] = Q;
    }
}

// ---------------- scan part3: per-block prefix + replay + y ----------------
__global__ __launch_bounds__(1024) void scan_part3(
    const float* __restrict__ Ad, const float* __restrict__ Bu,
    const float* __restrict__ Ct, const float* __restrict__ Pb,
    const float* __restrict__ Qb, const float* __restrict__ hprev,
    float* __restrict__ y, float* __restrict__ hfinal) {
    int b = blockIdx.x >> 6, g = blockIdx.x & 63;
    int tid = threadIdx.x;
    int s = tid & 15, c = tid >> 4;
    size_t idx = ((size_t)b * L_ + g * LC + c) * S_ + s;
    float a = Ad[idx], bu = Bu[idx];
    __shared__ float Ps[16][64], Qs[16][64], Hin[16][65];
    Ps[s][c] = a; Qs[s][c] = bu;
    __syncthreads();
    if (tid < 16) {
        float h = hprev[b * S_ + tid];
        for (int gg = 0; gg < g; gg++) {
            int o = (b * NBG + gg) * S_ + tid;
            h = Pb[o] * h + Qb[o];
        }
        for (int cc = 0; cc < 64; cc++) {
            Hin[tid][cc] = h;
            h = Ps[tid][cc] * h + Qs[tid][cc];
        }
        if (g == NBG - 1) hfinal[b * S_ + tid] = h;
    }
    __syncthreads();
    float h = a * Hin[s][c] + bu;
    float p = Ct[idx] * h;
    p += __shfl_xor(p, 1);
    p += __shfl_xor(p, 2);
    p += __shfl_xor(p, 4);
    p += __shfl_xor(p, 8);
    if (s == 0) y[(size_t)b * L_ + g * LC + c] = p;
}

extern "C" void kernel_launch(void* const* d_in, const int* in_sizes, int n_in,
                              void* d_out, int out_size, void* d_ws, size_t ws_size,
                              hipStream_t stream) {
    const float* x_seq  = (const float*)d_in[0];
    const float* h_prev = (const float*)d_in[1];
    const float* gamma  = (const float*)d_in[2];
    const float* beta   = (const float*)d_in[3];
    const float* W_in   = (const float*)d_in[4];
    const float* b_in   = (const float*)d_in[5];
    const float* W_A    = (const float*)d_in[6];
    const float* b_A    = (const float*)d_in[7];
    const float* W_B    = (const float*)d_in[8];
    const float* b_B    = (const float*)d_in[9];
    const float* W_C    = (const float*)d_in[10];
    const float* b_C    = (const float*)d_in[11];
    const float* W_dt   = (const float*)d_in[12];
    const float* b_dt   = (const float*)d_in[13];
    const float* W_out  = (const float*)d_in[14];
    const float* b_out  = (const float*)d_in[15];

    char* ws = (char*)d_ws;
    u16*   x_ln   = (u16*)(ws + 0);          // 33554432 B
    u16*   x      = (u16*)(ws + 33554432);   // 33554432 B
    u16*   Wt_in  = (u16*)(ws + 67108864);   // 2097152 B
    u16*   Wt_out = (u16*)(ws + 69206016);   // 2097152 B
    u16*   Wp     = (u16*)(ws + 71303168);   // 131072 B
    float* Ad     = (float*)(ws + 71434240); // 1048576 B
    float* Bu     = (float*)(ws + 72482816); // 1048576 B
    float* Ct     = (float*)(ws + 73531392); // 1048576 B
    float* yv     = (float*)(ws + 74579968); // 65536 B
    float* Pb     = (float*)(ws + 74645504); // 16384 B
    float* Qb     = (float*)(ws + 74661888); // 16384 B
    float* out    = (float*)d_out;

    ln_prep_kernel<<<M_ / 4 + 2048 + 256, 256, 0, stream>>>(
        x_seq, gamma, beta, x_ln,
        W_in, Wt_in, W_out, Wt_out, W_A, W_B, W_C, W_dt, Wp);
    gemm256<1><<<(M_ / 256) * (D_ / 256), 256, 0, stream>>>(
        x_ln, Wt_in, b_in, nullptr, nullptr, x, nullptr, M_, D_, D_, D_ / 256);
    proj_kernel<<<M_ / 64, 256, 0, stream>>>(x, Wp, b_A, b_B, b_C, b_dt,
                                             Ad, Bu, Ct, Pb, Qb);
    scan_part3<<<B_ * NBG, 1024, 0, stream>>>(Ad, Bu, Ct, Pb, Qb, h_prev,
                                              yv, out + (size_t)M_ * D_);
    gemm256<2><<<(M_ / 256) * (D_ / 256), 256, 0, stream>>>(
        x, Wt_out, b_out, x_seq, yv, nullptr, out, M_, D_, D_, D_ / 256);
}

// Round 15
// 148.841 us; speedup vs baseline: 1.1118x; 1.1118x over previous
//
#include <hip/hip_runtime.h>

typedef unsigned short u16;
typedef unsigned int u32;
typedef __attribute__((ext_vector_type(8))) short short8;
typedef __attribute__((ext_vector_type(4))) float f32x4;

#define B_ 4
#define L_ 4096
#define D_ 1024
#define S_ 16
#define M_ (B_ * L_)   // 16384 rows
#define NBG 64         // scan chunks per batch
#define LC 64          // timesteps per chunk

__device__ __forceinline__ float b2f(u16 h) {
    unsigned u = ((unsigned)h) << 16;
    return __builtin_bit_cast(float, u);
}
__device__ __forceinline__ u16 f2b(float f) {
    unsigned u = __builtin_bit_cast(unsigned, f);
    u += 0x7fffu + ((u >> 16) & 1u);   // RNE
    return (u16)(u >> 16);
}
__device__ __forceinline__ float softplus_f(float z) {
    return z > 20.f ? z : log1pf(__expf(z));
}
__device__ __forceinline__ void gload16(const u16* g, const u16* l) {
    __builtin_amdgcn_global_load_lds(
        (const __attribute__((address_space(1))) u32*)g,
        (__attribute__((address_space(3))) u32*)l, 16, 0, 0);
}

// ---------------- fused: LayerNorm (wave-per-row) + weight transposes + Wp pack ----------------
// blocks 0..4095: 4 rows each (one wave per row, shuffle-only reduce, no barriers)
// blocks 4096..6143: weight transpose    blocks 6144..6399: Wp pack
__global__ __launch_bounds__(256) void ln_prep_kernel(
    const float* __restrict__ x, const float* __restrict__ gamma,
    const float* __restrict__ beta, u16* __restrict__ xout,
    const float* __restrict__ W0, u16* __restrict__ Wt0,
    const float* __restrict__ W1, u16* __restrict__ Wt1,
    const float* __restrict__ WA, const float* __restrict__ WB,
    const float* __restrict__ WC, const float* __restrict__ Wdt,
    u16* __restrict__ Wp) {
    int blk = blockIdx.x, tid = threadIdx.x;
    if (blk < M_ / 4) {
        int w = tid >> 6, lane = tid & 63;
        int row = blk * 4 + w;
        const float* xr = &x[(size_t)row * D_];
        float4 v[4];
        float s = 0.f, q = 0.f;
#pragma unroll
        for (int i = 0; i < 4; i++) {
            v[i] = *(const float4*)&xr[(i * 64 + lane) * 4];
            s += v[i].x + v[i].y + v[i].z + v[i].w;
            q += v[i].x * v[i].x + v[i].y * v[i].y + v[i].z * v[i].z + v[i].w * v[i].w;
        }
#pragma unroll
        for (int o = 32; o > 0; o >>= 1) {
            s += __shfl_xor(s, o);
            q += __shfl_xor(q, o);
        }
        float mu = s * (1.f / D_);
        float rs = rsqrtf(q * (1.f / D_) - mu * mu + 1e-5f);
        u16* orow = &xout[(size_t)row * D_];
#pragma unroll
        for (int i = 0; i < 4; i++) {
            const float4 gv = *(const float4*)&gamma[(i * 64 + lane) * 4];
            const float4 bv = *(const float4*)&beta[(i * 64 + lane) * 4];
            ushort4 o4;
            o4.x = f2b((v[i].x - mu) * rs * gv.x + bv.x);
            o4.y = f2b((v[i].y - mu) * rs * gv.y + bv.y);
            o4.z = f2b((v[i].z - mu) * rs * gv.z + bv.z);
            o4.w = f2b((v[i].w - mu) * rs * gv.w + bv.w);
            *(ushort4*)&orow[(i * 64 + lane) * 4] = o4;
        }
    } else if (blk < M_ / 4 + 2048) {
        int b = blk - M_ / 4;
        const float* W = (b >> 10) ? W1 : W0;
        u16* Wt = (b >> 10) ? Wt1 : Wt0;
        int by = (b >> 5) & 31, bx = b & 31;
        int xx = tid & 31, ty = tid >> 5;
        __shared__ float t[32][33];
        for (int j = ty; j < 32; j += 8)
            t[j][xx] = W[(size_t)(by * 32 + j) * D_ + bx * 32 + xx];
        __syncthreads();
        for (int j = ty; j < 32; j += 8)
            Wt[(size_t)(bx * 32 + j) * D_ + by * 32 + xx] = f2b(t[xx][j]);
    } else {
        int idx = (blk - M_ / 4 - 2048) * 256 + tid;   // 0..65535
        int s = idx >> 10, k = idx & 1023;
        float v;
        if (s < 16)       v = WA[k * 16 + s];
        else if (s < 32)  v = WB[k * 16 + (s - 16)];
        else if (s < 48)  v = WC[k * 16 + (s - 32)];
        else if (s == 48) v = Wdt[k];
        else if (s == 49) v = 1.0f / 1024.0f;
        else              v = 0.f;
        Wp[idx] = f2b(v);
    }
}

// ================= 256x256 8-phase GEMM (round-6 structure, best measured) =================
// EPI==1: silu(acc+bias) -> bf16 via LDS-coalesced stores
// EPI==2: yrow[row]*acc + bias + resid -> fp32 direct
template <int EPI>
__global__ __launch_bounds__(512, 1) void gemm256(
    const u16* __restrict__ A, const u16* __restrict__ Bt,
    const float* __restrict__ bias, const float* __restrict__ resid,
    const float* __restrict__ yrow,
    u16* __restrict__ outB, float* __restrict__ outF,
    int M, int N, int K, int nTileN) {
    __shared__ u16 sm[65536];   // 128 KiB: [2 buf][A 16384 | B 16384]; reused by epilogue
    const int TILES = K >> 6;

    int nwg = gridDim.x;
    int bid = blockIdx.x;
    int swz = (bid & 7) * (nwg >> 3) + (bid >> 3);
    int bx = swz % nTileN, by = swz / nTileN;
    int rowBase = by * 256, colBase = bx * 256;

    int tid = threadIdx.x;
    int lane = tid & 63, w = tid >> 6;
    int wr = w >> 2, wc = w & 3;        // wave grid 2(M) x 4(N)
    int lr = lane & 15, lg = lane >> 4;
    const unsigned woff = (unsigned)((lr * 32 + lg * 8) ^ ((lr & 8) ? 16 : 0));

    int sub = w;
    int pos = sub >> 1;
    int kblk = sub & 1;
    int r = lane >> 2;
    int chunk = (lane & 3) ^ ((r & 8) ? 2 : 0);
    int rowoff = (pos & 1) * 16 + (pos >> 1) * 128;
    const u16* gAs = A  + (size_t)(rowBase + rowoff + r) * K + kblk * 32 + chunk * 8;
    const u16* gBs = Bt + (size_t)(colBase + rowoff + r) * K + kblk * 32 + chunk * 8;
    const unsigned subb = (unsigned)sub * 512u;

#define STAGEPAIR(tau, p)                                                        \
    do {                                                                         \
        unsigned _bb = (unsigned)((tau) & 1) * 32768u;                           \
        size_t _go = (size_t)(p) * 32 * K + (size_t)(tau) * 64;                  \
        gload16(gBs + _go, &sm[_bb + 16384u + (unsigned)(p) * 4096u + subb]);    \
        gload16(gAs + _go, &sm[_bb + (unsigned)(p) * 4096u + subb]);             \
    } while (0)

    f32x4 acc[8][4] = {};

    STAGEPAIR(0, 0); STAGEPAIR(0, 1); STAGEPAIR(0, 2); STAGEPAIR(0, 3);
    if (TILES > 1) { STAGEPAIR(1, 0); STAGEPAIR(1, 1); STAGEPAIR(1, 2); }
    asm volatile("s_waitcnt vmcnt(6)" ::: "memory");
    __builtin_amdgcn_s_barrier();

    for (int t = 0; t < TILES; ++t) {
        const unsigned bb = (unsigned)(t & 1) * 32768u;
        short8 bfr[4][2], afr[2][2];
        // ---------- phase 0: stage {B3,A3 of t+1} first, then read all B + A region0
        if (t + 1 < TILES) STAGEPAIR(t + 1, 3);
#pragma unroll
        for (int n = 0; n < 4; n++) {
            int rb = wc * 4 + n;
            unsigned bo = bb + 16384u + (unsigned)(((rb & 7) >> 1)) * 4096u
                        + (unsigned)(((rb & 1) + ((rb >> 3) << 1)) << 1) * 512u + woff;
            bfr[n][0] = *(const short8*)&sm[bo];
            bfr[n][1] = *(const short8*)&sm[bo + 512u];
        }
#pragma unroll
        for (int dm = 0; dm < 2; dm++) {
            unsigned ao = bb + (unsigned)((dm + (wr << 1)) << 1) * 512u + woff;
            afr[dm][0] = *(const short8*)&sm[ao];
            afr[dm][1] = *(const short8*)&sm[ao + 512u];
        }
        __builtin_amdgcn_s_barrier();
        __builtin_amdgcn_s_setprio(1);
#pragma unroll
        for (int dm = 0; dm < 2; dm++)
#pragma unroll
            for (int n = 0; n < 4; n++)
#pragma unroll
                for (int ks = 0; ks < 2; ks++)
                    acc[dm][n] = __builtin_amdgcn_mfma_f32_16x16x32_bf16(
                        afr[dm][ks], bfr[n][ks], acc[dm][n], 0, 0, 0);
        __builtin_amdgcn_s_setprio(0);
        __builtin_amdgcn_s_barrier();
        // ---------- phases 1..3: stage {B(q-1),A(q-1) of t+2} first, then read A region q
#pragma unroll
        for (int q = 1; q < 4; q++) {
            if (t + 2 < TILES) STAGEPAIR(t + 2, q - 1);
#pragma unroll
            for (int dm = 0; dm < 2; dm++) {
                int m = q * 2 + dm;
                unsigned ao = bb + (unsigned)q * 4096u
                            + (unsigned)(((m & 1) + (wr << 1)) << 1) * 512u + woff;
                afr[dm][0] = *(const short8*)&sm[ao];
                afr[dm][1] = *(const short8*)&sm[ao + 512u];
            }
            __builtin_amdgcn_s_barrier();
            __builtin_amdgcn_s_setprio(1);
#pragma unroll
            for (int dm = 0; dm < 2; dm++)
#pragma unroll
                for (int n = 0; n < 4; n++)
#pragma unroll
                    for (int ks = 0; ks < 2; ks++)
                        acc[q * 2 + dm][n] = __builtin_amdgcn_mfma_f32_16x16x32_bf16(
                            afr[dm][ks], bfr[n][ks], acc[q * 2 + dm][n], 0, 0, 0);
            __builtin_amdgcn_s_setprio(0);
            if (q == 3) {   // tile-end gate BEFORE closing barrier
                if (t + 2 < TILES)      asm volatile("s_waitcnt vmcnt(6)" ::: "memory");
                else if (t + 1 < TILES) asm volatile("s_waitcnt vmcnt(0)" ::: "memory");
            }
            __builtin_amdgcn_s_barrier();
        }
    }
#undef STAGEPAIR

    // ---------- epilogue
    if (EPI == 1) {
        float bcol[4];
#pragma unroll
        for (int n = 0; n < 4; n++) bcol[n] = bias[colBase + wc * 64 + n * 16 + lr];
#pragma unroll
        for (int m = 0; m < 8; m++)
#pragma unroll
            for (int n = 0; n < 4; n++)
#pragma unroll
                for (int j = 0; j < 4; j++) {
                    int row = wr * 128 + m * 16 + lg * 4 + j;
                    int col = wc * 64 + n * 16 + lr;
                    float v = acc[m][n][j] + bcol[n];
                    v = v / (1.f + __expf(-v));     // silu
                    int cbs = (col >> 4) ^ lg;      // (row>>2)&3 == lg
                    sm[row * 256 + cbs * 16 + (col & 15)] = f2b(v);
                }
        __syncthreads();
        int rr = tid >> 1, half = tid & 1;
        u16* gout = outB + (size_t)(rowBase + rr) * N + colBase;
#pragma unroll
        for (int q = 0; q < 8; q++) {
            int cb = half * 8 + q;
            int cbs = cb ^ ((rr >> 2) & 3);
            *(uint4*)&gout[cb * 16] = *(const uint4*)&sm[rr * 256 + cbs * 16];
        }
    } else {
        float bcol[4];
#pragma unroll
        for (int n = 0; n < 4; n++) bcol[n] = bias[colBase + wc * 64 + n * 16 + lr];
#pragma unroll
        for (int m = 0; m < 8; m++) {
            float yr[4];
#pragma unroll
            for (int j = 0; j < 4; j++)
                yr[j] = yrow[rowBase + wr * 128 + m * 16 + lg * 4 + j];
#pragma unroll
            for (int n = 0; n < 4; n++)
#pragma unroll
                for (int j = 0; j < 4; j++) {
                    int row = rowBase + wr * 128 + m * 16 + lg * 4 + j;
                    int col = colBase + wc * 64 + n * 16 + lr;
                    size_t o = (size_t)row * N + col;
                    outF[o] = acc[m][n][j] * yr[j] + bcol[n] + resid[o];
                }
        }
    }
}

// ---------------- projection GEMM + fused per-chunk scan partials ----------------
__global__ __launch_bounds__(256) void proj_kernel(
    const u16* __restrict__ X, const u16* __restrict__ Wp,
    const float* __restrict__ bA, const float* __restrict__ bB,
    const float* __restrict__ bC, const float* __restrict__ bdt,
    float* __restrict__ Ad, float* __restrict__ Bu, float* __restrict__ Ct,
    float* __restrict__ Pb, float* __restrict__ Qb) {
    __shared__ u16 Xs[2][64][32];
    __shared__ u16 Ws[2][64][32];
    __shared__ float Psh[64][17], Qsh[64][17];
    int rowBase = blockIdx.x * 64;
    int tid = threadIdx.x, lane = tid & 63, w = tid >> 6;
    int lr = lane & 15, lg = lane >> 4;
    f32x4 acc[4] = {};
    const int sr = lane >> 2, sc = (lane & 3) * 8;
    const u16* gX = &X[(size_t)(rowBase + w * 16 + sr) * 1024 + sc];
    const u16* gW = &Wp[(size_t)(w * 16 + sr) * 1024 + sc];

#define PSTAGE(d, k0)                              \
    do {                                           \
        gload16(gX + (k0), &Xs[d][w * 16][0]);     \
        gload16(gW + (k0), &Ws[d][w * 16][0]);     \
    } while (0)

    PSTAGE(0, 0);
    __syncthreads();
    int cur = 0;
    for (int k0 = 0; k0 < 1024; k0 += 32) {
        if (k0 + 32 < 1024) PSTAGE(cur ^ 1, k0 + 32);
        short8 a = *(const short8*)&Xs[cur][w * 16 + lr][lg * 8];
#pragma unroll
        for (int n = 0; n < 4; n++) {
            short8 b = *(const short8*)&Ws[cur][n * 16 + lr][lg * 8];
            acc[n] = __builtin_amdgcn_mfma_f32_16x16x32_bf16(a, b, acc[n], 0, 0, 0);
        }
        __syncthreads();
        cur ^= 1;
    }
#undef PSTAGE
    float bdt0 = bdt[0];
#pragma unroll
    for (int j = 0; j < 4; j++) {
        int rl = w * 16 + lg * 4 + j;              // row within chunk, 0..63
        int row = rowBase + rl;
        float dtr = __shfl(acc[3][j], lg * 16 + 0, 64);   // col 48 = z_dt
        float uv  = __shfl(acc[3][j], lg * 16 + 1, 64);   // col 49 = u (mean)
        float dt = softplus_f(dtr + bdt0);
        float zA = acc[0][j] + bA[lr];
        float zB = acc[1][j] + bB[lr];
        float zC = acc[2][j] + bC[lr];
        size_t o = (size_t)row * 16 + lr;
        float adv = __expf(-dt * softplus_f(zA));
        float buv = zB * dt * uv;
        Ad[o] = adv;
        Bu[o] = buv;
        Ct[o] = zC;
        Psh[rl][lr] = adv;
        Qsh[rl][lr] = buv;
    }
    __syncthreads();
    if (tid < 16) {
        float P = 1.f, Q = 0.f;
        for (int rr = 0; rr < 64; rr++) {
            float pa = Psh[rr][tid];
            P = pa * P;
            Q = pa * Q + Qsh[rr][tid];
        }
        int o = blockIdx.x * S_ + tid;   // blockIdx == b*NBG + g
        Pb[o] = P; Qb[o] = Q;
    }
}

// ---------------- scan part3: per-block prefix + replay + y ----------------
__global__ __launch_bounds__(1024) void scan_part3(
    const float* __restrict__ Ad, const float* __restrict__ Bu,
    const float* __restrict__ Ct, const float* __restrict__ Pb,
    const float* __restrict__ Qb, const float* __restrict__ hprev,
    float* __restrict__ y, float* __restrict__ hfinal) {
    int b = blockIdx.x >> 6, g = blockIdx.x & 63;
    int tid = threadIdx.x;
    int s = tid & 15, c = tid >> 4;
    size_t idx = ((size_t)b * L_ + g * LC + c) * S_ + s;
    float a = Ad[idx], bu = Bu[idx];
    __shared__ float Ps[16][64], Qs[16][64], Hin[16][65];
    Ps[s][c] = a; Qs[s][c] = bu;
    __syncthreads();
    if (tid < 16) {
        float h = hprev[b * S_ + tid];
        for (int gg = 0; gg < g; gg++) {
            int o = (b * NBG + gg) * S_ + tid;
            h = Pb[o] * h + Qb[o];
        }
        for (int cc = 0; cc < 64; cc++) {
            Hin[tid][cc] = h;
            h = Ps[tid][cc] * h + Qs[tid][cc];
        }
        if (g == NBG - 1) hfinal[b * S_ + tid] = h;
    }
    __syncthreads();
    float h = a * Hin[s][c] + bu;
    float p = Ct[idx] * h;
    p += __shfl_xor(p, 1);
    p += __shfl_xor(p, 2);
    p += __shfl_xor(p, 4);
    p += __shfl_xor(p, 8);
    if (s == 0) y[(size_t)b * L_ + g * LC + c] = p;
}

extern "C" void kernel_launch(void* const* d_in, const int* in_sizes, int n_in,
                              void* d_out, int out_size, void* d_ws, size_t ws_size,
                              hipStream_t stream) {
    const float* x_seq  = (const float*)d_in[0];
    const float* h_prev = (const float*)d_in[1];
    const float* gamma  = (const float*)d_in[2];
    const float* beta   = (const float*)d_in[3];
    const float* W_in   = (const float*)d_in[4];
    const float* b_in   = (const float*)d_in[5];
    const float* W_A    = (const float*)d_in[6];
    const float* b_A    = (const float*)d_in[7];
    const float* W_B    = (const float*)d_in[8];
    const float* b_B    = (const float*)d_in[9];
    const float* W_C    = (const float*)d_in[10];
    const float* b_C    = (const float*)d_in[11];
    const float* W_dt   = (const float*)d_in[12];
    const float* b_dt   = (const float*)d_in[13];
    const float* W_out  = (const float*)d_in[14];
    const float* b_out  = (const float*)d_in[15];

    char* ws = (char*)d_ws;
    u16*   x_ln   = (u16*)(ws + 0);          // 33554432 B
    u16*   x      = (u16*)(ws + 33554432);   // 33554432 B
    u16*   Wt_in  = (u16*)(ws + 67108864);   // 2097152 B
    u16*   Wt_out = (u16*)(ws + 69206016);   // 2097152 B
    u16*   Wp     = (u16*)(ws + 71303168);   // 131072 B
    float* Ad     = (float*)(ws + 71434240); // 1048576 B
    float* Bu     = (float*)(ws + 72482816); // 1048576 B
    float* Ct     = (float*)(ws + 73531392); // 1048576 B
    float* yv     = (float*)(ws + 74579968); // 65536 B
    float* Pb     = (float*)(ws + 74645504); // 16384 B
    float* Qb     = (float*)(ws + 74661888); // 16384 B
    float* out    = (float*)d_out;

    ln_prep_kernel<<<M_ / 4 + 2048 + 256, 256, 0, stream>>>(
        x_seq, gamma, beta, x_ln,
        W_in, Wt_in, W_out, Wt_out, W_A, W_B, W_C, W_dt, Wp);
    gemm256<1><<<(M_ / 256) * (D_ / 256), 512, 0, stream>>>(
        x_ln, Wt_in, b_in, nullptr, nullptr, x, nullptr, M_, D_, D_, D_ / 256);
    proj_kernel<<<M_ / 64, 256, 0, stream>>>(x, Wp, b_A, b_B, b_C, b_dt,
                                             Ad, Bu, Ct, Pb, Qb);
    scan_part3<<<B_ * NBG, 1024, 0, stream>>>(Ad, Bu, Ct, Pb, Qb, h_prev,
                                              yv, out + (size_t)M_ * D_);
    gemm256<2><<<(M_ / 256) * (D_ / 256), 512, 0, stream>>>(
        x, Wt_out, b_out, x_seq, yv, nullptr, out, M_, D_, D_, D_ / 256);
}